// Round 1
// baseline (2519.496 us; speedup 1.0000x reference)
//
#include <hip/hip_runtime.h>

#define N_NODES 50000
#define DIM 128
#define BN_EPS 1e-5f

// ---------------------------------------------------------------------------
// agg[dst] += relu(h[src]); one wave per edge, 64 lanes x float2 = 512B row.
// ---------------------------------------------------------------------------
__global__ __launch_bounds__(256) void scatter_relu_add(
    const float* __restrict__ h, const int* __restrict__ src,
    const int* __restrict__ dst, float* __restrict__ agg, int E) {
  const int wid = (blockIdx.x * blockDim.x + threadIdx.x) >> 6;
  const int lane = threadIdx.x & 63;
  const int nw = (gridDim.x * blockDim.x) >> 6;
  for (int e = wid; e < E; e += nw) {
    const int s = src[e];
    const int d = dst[e];
    const float2 v =
        *reinterpret_cast<const float2*>(h + (size_t)s * DIM + lane * 2);
    float* p = agg + (size_t)d * DIM + lane * 2;
    if (v.x > 0.f) atomicAdd(p, v.x);
    if (v.y > 0.f) atomicAdd(p + 1, v.y);
  }
}

// ---------------------------------------------------------------------------
// Fused GEMM: out[i][j] = sum_k z[i][k] * W[k][j] + bias[j]
//   MODE 0: z = (1+eps)*h + agg          (GIN combine, start of MLP)
//   MODE 1: z = relu(a[k]*t[i][k]+c[k])  (BN1-apply + ReLU fused on load)
// Epilogue: per-column sum / sumsq accumulated into stats[] (for the next BN).
// Block: 256 thr, 64 rows x 128 cols, K chunked by 32. In-place out==in safe
// (each block reads all its rows into LDS before writing them).
// ---------------------------------------------------------------------------
template <int MODE>
__global__ __launch_bounds__(256) void gemm_bn(
    const float* __restrict__ in0,   // MODE0: h      MODE1: t1
    const float* __restrict__ in1,   // MODE0: agg    MODE1: unused
    const float* __restrict__ ac,    // MODE0: &eps[l] MODE1: a[128],c[128]
    const float* __restrict__ W,     // [128][128] row-major (k, j)
    const float* __restrict__ bias,  // [128]
    float* __restrict__ out,         // [N][128]
    float* __restrict__ stats) {     // sum[128], sumsq[128]
  __shared__ float w_lds[32][DIM];   // 16 KB
  __shared__ float z_lds[64][32];    // 8 KB

  const int tid = threadIdx.x;
  const int group = tid >> 5;  // 0..7 (each group of 32 lanes: 8 rows)
  const int lane = tid & 31;   // col chunk: 4 cols per lane
  const int row0 = blockIdx.x * 64;

  float4 acc[8];
#pragma unroll
  for (int r = 0; r < 8; ++r) acc[r] = make_float4(0.f, 0.f, 0.f, 0.f);

  const float epsv = (MODE == 0) ? (1.0f + ac[0]) : 0.f;

  for (int kc = 0; kc < 4; ++kc) {
    const int kbase = kc * 32;
    // ---- stage W chunk [32][128] (contiguous per 8-lane phase: no conflicts)
#pragma unroll
    for (int it = 0; it < 4; ++it) {
      const int krow = (tid >> 5) + it * 8;
      const int j4 = (tid & 31) * 4;
      *reinterpret_cast<float4*>(&w_lds[krow][j4]) =
          *reinterpret_cast<const float4*>(&W[(size_t)(kbase + krow) * DIM + j4]);
    }
    // ---- stage z chunk [64][32] with fused prologue transform
#pragma unroll
    for (int it = 0; it < 2; ++it) {
      const int rl = (tid >> 3) + it * 32;  // 0..63
      const int kk4 = (tid & 7) * 4;
      const int rowg = row0 + rl;
      float4 z = make_float4(0.f, 0.f, 0.f, 0.f);
      if (rowg < N_NODES) {
        const size_t off = (size_t)rowg * DIM + kbase + kk4;
        if (MODE == 0) {
          const float4 hv = *reinterpret_cast<const float4*>(&in0[off]);
          const float4 av = *reinterpret_cast<const float4*>(&in1[off]);
          z.x = epsv * hv.x + av.x;
          z.y = epsv * hv.y + av.y;
          z.z = epsv * hv.z + av.z;
          z.w = epsv * hv.w + av.w;
        } else {
          const float4 tv = *reinterpret_cast<const float4*>(&in0[off]);
          const float4 aa =
              *reinterpret_cast<const float4*>(&ac[kbase + kk4]);
          const float4 cc =
              *reinterpret_cast<const float4*>(&ac[DIM + kbase + kk4]);
          z.x = fmaxf(aa.x * tv.x + cc.x, 0.f);
          z.y = fmaxf(aa.y * tv.y + cc.y, 0.f);
          z.z = fmaxf(aa.z * tv.z + cc.z, 0.f);
          z.w = fmaxf(aa.w * tv.w + cc.w, 0.f);
        }
      }
      *reinterpret_cast<float4*>(&z_lds[rl][kk4]) = z;
    }
    __syncthreads();
    // ---- compute: per 4k: 4 W b128 + 8 z b128(broadcast) + 128 FMA
#pragma unroll
    for (int k = 0; k < 32; k += 4) {
      const float4 w0 = *reinterpret_cast<const float4*>(&w_lds[k + 0][lane * 4]);
      const float4 w1 = *reinterpret_cast<const float4*>(&w_lds[k + 1][lane * 4]);
      const float4 w2 = *reinterpret_cast<const float4*>(&w_lds[k + 2][lane * 4]);
      const float4 w3 = *reinterpret_cast<const float4*>(&w_lds[k + 3][lane * 4]);
#pragma unroll
      for (int r = 0; r < 8; ++r) {
        const float4 z4 =
            *reinterpret_cast<const float4*>(&z_lds[group * 8 + r][k]);
        acc[r].x += z4.x * w0.x + z4.y * w1.x + z4.z * w2.x + z4.w * w3.x;
        acc[r].y += z4.x * w0.y + z4.y * w1.y + z4.z * w2.y + z4.w * w3.y;
        acc[r].z += z4.x * w0.z + z4.y * w1.z + z4.z * w2.z + z4.w * w3.z;
        acc[r].w += z4.x * w0.w + z4.y * w1.w + z4.z * w2.w + z4.w * w3.w;
      }
    }
    __syncthreads();
  }

  // ---- epilogue: +bias, store, per-column partial stats
  const float4 bv = *reinterpret_cast<const float4*>(&bias[lane * 4]);
  float4 s1 = make_float4(0.f, 0.f, 0.f, 0.f);
  float4 s2 = make_float4(0.f, 0.f, 0.f, 0.f);
#pragma unroll
  for (int r = 0; r < 8; ++r) {
    const int rowg = row0 + group * 8 + r;
    if (rowg < N_NODES) {
      float4 v;
      v.x = acc[r].x + bv.x;
      v.y = acc[r].y + bv.y;
      v.z = acc[r].z + bv.z;
      v.w = acc[r].w + bv.w;
      *reinterpret_cast<float4*>(&out[(size_t)rowg * DIM + lane * 4]) = v;
      s1.x += v.x; s1.y += v.y; s1.z += v.z; s1.w += v.w;
      s2.x += v.x * v.x; s2.y += v.y * v.y; s2.z += v.z * v.z; s2.w += v.w * v.w;
    }
  }
  __syncthreads();  // w_lds no longer needed; reuse as reduction scratch
  float* red = &w_lds[0][0];  // 4096 floats: [0..1023]=sum, [1024..2047]=sumsq
  red[group * DIM + lane * 4 + 0] = s1.x;
  red[group * DIM + lane * 4 + 1] = s1.y;
  red[group * DIM + lane * 4 + 2] = s1.z;
  red[group * DIM + lane * 4 + 3] = s1.w;
  red[1024 + group * DIM + lane * 4 + 0] = s2.x;
  red[1024 + group * DIM + lane * 4 + 1] = s2.y;
  red[1024 + group * DIM + lane * 4 + 2] = s2.z;
  red[1024 + group * DIM + lane * 4 + 3] = s2.w;
  __syncthreads();
  if (tid < DIM) {
    float a = 0.f, b = 0.f;
#pragma unroll
    for (int g = 0; g < 8; ++g) {
      a += red[g * DIM + tid];
      b += red[1024 + g * DIM + tid];
    }
    atomicAdd(&stats[tid], a);
    atomicAdd(&stats[DIM + tid], b);
  }
}

// ---------------------------------------------------------------------------
// Fold (sum, sumsq) -> (a = g*rsqrt(var+eps), c = b - mu*a). One block.
// ---------------------------------------------------------------------------
__global__ void bn_param(const float* __restrict__ stats,
                         const float* __restrict__ g,
                         const float* __restrict__ b, float* __restrict__ ac) {
  const int j = threadIdx.x;
  const float invN = 1.0f / (float)N_NODES;
  const float mu = stats[j] * invN;
  const float var = stats[DIM + j] * invN - mu * mu;
  const float a = g[j] * rsqrtf(var + BN_EPS);
  ac[j] = a;
  ac[DIM + j] = b[j] - mu * a;
}

// ---------------------------------------------------------------------------
// h = (relu?)(a[k]*t + c[k]) elementwise; one float4 per thread, exact grid.
// ---------------------------------------------------------------------------
template <int RELU>
__global__ __launch_bounds__(256) void apply_bn(const float* __restrict__ t,
                                                const float* __restrict__ ac,
                                                float* __restrict__ out) {
  const int i = blockIdx.x * blockDim.x + threadIdx.x;  // N*D/4 threads
  const int k = (i * 4) & (DIM - 1);
  const float4 v = *reinterpret_cast<const float4*>(&t[(size_t)i * 4]);
  const float4 a = *reinterpret_cast<const float4*>(&ac[k]);
  const float4 c = *reinterpret_cast<const float4*>(&ac[DIM + k]);
  float4 r;
  r.x = a.x * v.x + c.x;
  r.y = a.y * v.y + c.y;
  r.z = a.z * v.z + c.z;
  r.w = a.w * v.w + c.w;
  if (RELU) {
    r.x = fmaxf(r.x, 0.f);
    r.y = fmaxf(r.y, 0.f);
    r.z = fmaxf(r.z, 0.f);
    r.w = fmaxf(r.w, 0.f);
  }
  *reinterpret_cast<float4*>(&out[(size_t)i * 4]) = r;
}

extern "C" void kernel_launch(void* const* d_in, const int* in_sizes, int n_in,
                              void* d_out, int out_size, void* d_ws,
                              size_t ws_size, hipStream_t stream) {
  const float* x = (const float*)d_in[0];
  const int* ei = (const int*)d_in[1];  // [2][E]: src = ei, dst = ei+E
  const float* eps = (const float*)d_in[2];
  const float* W1 = (const float*)d_in[3];
  const float* b1 = (const float*)d_in[4];
  const float* g1 = (const float*)d_in[5];
  const float* bb1 = (const float*)d_in[6];
  const float* W2 = (const float*)d_in[7];
  const float* b2 = (const float*)d_in[8];
  const float* g2 = (const float*)d_in[9];
  const float* bb2 = (const float*)d_in[10];

  const int E = in_sizes[1] / 2;

  float* bufA = (float*)d_ws;                        // agg/t1/t2 (25.6 MB)
  float* bufH = bufA + (size_t)N_NODES * DIM;        // h ping buffer (25.6 MB)
  float* stats = bufH + (size_t)N_NODES * DIM;       // 512 floats
  float* bnp = stats + 512;                          // 512 floats (a1,c1,a2,c2)

  const int gemm_grid = (N_NODES + 63) / 64;         // 782
  const int apply_grid = (N_NODES * DIM / 4) / 256;  // 6250 (exact)

  const float* h = x;
  for (int l = 0; l < 3; ++l) {
    hipMemsetAsync(bufA, 0, sizeof(float) * (size_t)N_NODES * DIM, stream);
    hipMemsetAsync(stats, 0, sizeof(float) * 512, stream);
    scatter_relu_add<<<2048, 256, 0, stream>>>(h, ei, ei + E, bufA, E);
    gemm_bn<0><<<gemm_grid, 256, 0, stream>>>(h, bufA, eps + l,
                                              W1 + (size_t)l * DIM * DIM,
                                              b1 + l * DIM, bufA, stats);
    bn_param<<<1, DIM, 0, stream>>>(stats, g1 + l * DIM, bb1 + l * DIM, bnp);
    gemm_bn<1><<<gemm_grid, 256, 0, stream>>>(bufA, bufA, bnp,
                                              W2 + (size_t)l * DIM * DIM,
                                              b2 + l * DIM, bufA, stats + 256);
    bn_param<<<1, DIM, 0, stream>>>(stats + 256, g2 + l * DIM, bb2 + l * DIM,
                                    bnp + 256);
    if (l < 2) {
      apply_bn<1><<<apply_grid, 256, 0, stream>>>(bufA, bnp + 256, bufH);
      h = bufH;
    } else {
      apply_bn<0><<<apply_grid, 256, 0, stream>>>(bufA, bnp + 256,
                                                  (float*)d_out);
    }
  }
}

// Round 2
// 878.700 us; speedup vs baseline: 2.8673x; 2.8673x over previous
//
#include <hip/hip_runtime.h>

#define N_NODES 50000
#define DIM 128
#define BN_EPS 1e-5f

// ===========================================================================
// CSR build (once per call; graph is identical across the 3 layers)
// ===========================================================================
__global__ __launch_bounds__(256) void edge_hist(const int* __restrict__ dst,
                                                 int* __restrict__ cnt, int E) {
  const int e = blockIdx.x * blockDim.x + threadIdx.x;
  if (e < E) atomicAdd(&cnt[dst[e]], 1);
}

// Exclusive scan of cnt[0..N) -> row_ptr[0..N]; single block of 1024.
__global__ __launch_bounds__(1024) void edge_scan(const int* __restrict__ cnt,
                                                  int* __restrict__ row_ptr) {
  __shared__ int part[1024];
  const int tid = threadIdx.x;
  const int per = (N_NODES + 1023) / 1024;  // 49
  const int start = tid * per;
  const int end = min(start + per, N_NODES);
  int s = 0;
  for (int i = start; i < end; ++i) s += cnt[i];
  part[tid] = s;
  __syncthreads();
  for (int off = 1; off < 1024; off <<= 1) {
    const int v = part[tid];
    const int u = (tid >= off) ? part[tid - off] : 0;
    __syncthreads();
    part[tid] = v + u;  // inclusive scan
    __syncthreads();
  }
  int run = (tid == 0) ? 0 : part[tid - 1];
  for (int i = start; i < end; ++i) {
    row_ptr[i] = run;
    run += cnt[i];
  }
  if (tid == 1023) row_ptr[N_NODES] = run;  // == E
}

__global__ __launch_bounds__(256) void edge_fill(const int* __restrict__ src,
                                                 const int* __restrict__ dst,
                                                 const int* __restrict__ row_ptr,
                                                 int* __restrict__ cur,
                                                 int* __restrict__ srcl, int E) {
  const int e = blockIdx.x * blockDim.x + threadIdx.x;
  if (e < E) {
    const int d = dst[e];
    const int pos = row_ptr[d] + atomicAdd(&cur[d], 1);
    srcl[pos] = src[e];
  }
}

// ===========================================================================
// Aggregation (gather form) fused with GIN combine:
//   z[i] = (1+eps)*h[i] + sum_{j in nbrs(i)} relu(h[j])
// One wave per node; lane handles float2 (64*8B = 512B row). No atomics.
// ===========================================================================
__global__ __launch_bounds__(256) void aggregate_combine(
    const float* __restrict__ h, const int* __restrict__ row_ptr,
    const int* __restrict__ srcl, const float* __restrict__ eps_l,
    float* __restrict__ z) {
  const int node = (blockIdx.x * blockDim.x + threadIdx.x) >> 6;
  const int lane = threadIdx.x & 63;
  if (node >= N_NODES) return;
  const float epsv = 1.0f + *eps_l;
  const size_t col = (size_t)lane * 2;
  float2 acc;
  {
    const float2 hv = *reinterpret_cast<const float2*>(h + (size_t)node * DIM + col);
    acc.x = epsv * hv.x;
    acc.y = epsv * hv.y;
  }
  int p = row_ptr[node];
  const int pe = row_ptr[node + 1];
  for (; p + 4 <= pe; p += 4) {  // 4-deep ILP to hide L2/L3 latency
    const int s0 = srcl[p + 0], s1 = srcl[p + 1];
    const int s2 = srcl[p + 2], s3 = srcl[p + 3];
    const float2 v0 = *reinterpret_cast<const float2*>(h + (size_t)s0 * DIM + col);
    const float2 v1 = *reinterpret_cast<const float2*>(h + (size_t)s1 * DIM + col);
    const float2 v2 = *reinterpret_cast<const float2*>(h + (size_t)s2 * DIM + col);
    const float2 v3 = *reinterpret_cast<const float2*>(h + (size_t)s3 * DIM + col);
    acc.x += fmaxf(v0.x, 0.f) + fmaxf(v1.x, 0.f) + fmaxf(v2.x, 0.f) + fmaxf(v3.x, 0.f);
    acc.y += fmaxf(v0.y, 0.f) + fmaxf(v1.y, 0.f) + fmaxf(v2.y, 0.f) + fmaxf(v3.y, 0.f);
  }
  for (; p < pe; ++p) {
    const int s = srcl[p];
    const float2 v = *reinterpret_cast<const float2*>(h + (size_t)s * DIM + col);
    acc.x += fmaxf(v.x, 0.f);
    acc.y += fmaxf(v.y, 0.f);
  }
  *reinterpret_cast<float2*>(z + (size_t)node * DIM + col) = acc;
}

// ===========================================================================
// Fused GEMM: out[i][j] = sum_k f(z[i][k]) * W[k][j] + bias[j]
//   MODE 2: f = identity (z precomputed by aggregate_combine)
//   MODE 1: f = relu(a[k]*t + c[k])   (BN1-apply + ReLU fused on load)
// Epilogue: per-column sum/sumsq partials -> stats[] for the following BN.
// Block: 256 thr, 64 rows x 128 cols, K chunked by 32. In-place safe.
// ===========================================================================
template <int MODE>
__global__ __launch_bounds__(256) void gemm_bn(
    const float* __restrict__ in0,   // z (MODE2) or t1 (MODE1)
    const float* __restrict__ ac,    // MODE1: a[128],c[128]; MODE2 unused
    const float* __restrict__ W,     // [128][128] row-major (k, j)
    const float* __restrict__ bias,  // [128]
    float* __restrict__ out,         // [N][128]
    float* __restrict__ stats) {     // sum[128], sumsq[128]
  __shared__ float w_lds[32][DIM];   // 16 KB
  __shared__ float z_lds[64][32];    // 8 KB

  const int tid = threadIdx.x;
  const int group = tid >> 5;  // 0..7: rows group*8..group*8+7
  const int lane = tid & 31;   // cols lane*4..lane*4+3
  const int row0 = blockIdx.x * 64;

  float4 acc[8];
#pragma unroll
  for (int r = 0; r < 8; ++r) acc[r] = make_float4(0.f, 0.f, 0.f, 0.f);

  for (int kc = 0; kc < 4; ++kc) {
    const int kbase = kc * 32;
#pragma unroll
    for (int it = 0; it < 4; ++it) {
      const int krow = (tid >> 5) + it * 8;
      const int j4 = (tid & 31) * 4;
      *reinterpret_cast<float4*>(&w_lds[krow][j4]) =
          *reinterpret_cast<const float4*>(&W[(size_t)(kbase + krow) * DIM + j4]);
    }
#pragma unroll
    for (int it = 0; it < 2; ++it) {
      const int rl = (tid >> 3) + it * 32;  // 0..63
      const int kk4 = (tid & 7) * 4;
      const int rowg = row0 + rl;
      float4 z = make_float4(0.f, 0.f, 0.f, 0.f);
      if (rowg < N_NODES) {
        const size_t off = (size_t)rowg * DIM + kbase + kk4;
        const float4 tv = *reinterpret_cast<const float4*>(&in0[off]);
        if (MODE == 1) {
          const float4 aa = *reinterpret_cast<const float4*>(&ac[kbase + kk4]);
          const float4 cc = *reinterpret_cast<const float4*>(&ac[DIM + kbase + kk4]);
          z.x = fmaxf(aa.x * tv.x + cc.x, 0.f);
          z.y = fmaxf(aa.y * tv.y + cc.y, 0.f);
          z.z = fmaxf(aa.z * tv.z + cc.z, 0.f);
          z.w = fmaxf(aa.w * tv.w + cc.w, 0.f);
        } else {
          z = tv;
        }
      }
      *reinterpret_cast<float4*>(&z_lds[rl][kk4]) = z;
    }
    __syncthreads();
#pragma unroll
    for (int k = 0; k < 32; k += 4) {
      const float4 w0 = *reinterpret_cast<const float4*>(&w_lds[k + 0][lane * 4]);
      const float4 w1 = *reinterpret_cast<const float4*>(&w_lds[k + 1][lane * 4]);
      const float4 w2 = *reinterpret_cast<const float4*>(&w_lds[k + 2][lane * 4]);
      const float4 w3 = *reinterpret_cast<const float4*>(&w_lds[k + 3][lane * 4]);
#pragma unroll
      for (int r = 0; r < 8; ++r) {
        const float4 z4 =
            *reinterpret_cast<const float4*>(&z_lds[group * 8 + r][k]);
        acc[r].x += z4.x * w0.x + z4.y * w1.x + z4.z * w2.x + z4.w * w3.x;
        acc[r].y += z4.x * w0.y + z4.y * w1.y + z4.z * w2.y + z4.w * w3.y;
        acc[r].z += z4.x * w0.z + z4.y * w1.z + z4.z * w2.z + z4.w * w3.z;
        acc[r].w += z4.x * w0.w + z4.y * w1.w + z4.z * w2.w + z4.w * w3.w;
      }
    }
    __syncthreads();
  }

  const float4 bv = *reinterpret_cast<const float4*>(&bias[lane * 4]);
  float4 s1 = make_float4(0.f, 0.f, 0.f, 0.f);
  float4 s2 = make_float4(0.f, 0.f, 0.f, 0.f);
#pragma unroll
  for (int r = 0; r < 8; ++r) {
    const int rowg = row0 + group * 8 + r;
    if (rowg < N_NODES) {
      float4 v;
      v.x = acc[r].x + bv.x;
      v.y = acc[r].y + bv.y;
      v.z = acc[r].z + bv.z;
      v.w = acc[r].w + bv.w;
      *reinterpret_cast<float4*>(&out[(size_t)rowg * DIM + lane * 4]) = v;
      s1.x += v.x; s1.y += v.y; s1.z += v.z; s1.w += v.w;
      s2.x += v.x * v.x; s2.y += v.y * v.y; s2.z += v.z * v.z; s2.w += v.w * v.w;
    }
  }
  __syncthreads();
  float* red = &w_lds[0][0];  // reuse: [0..1023]=sum, [1024..2047]=sumsq
  red[group * DIM + lane * 4 + 0] = s1.x;
  red[group * DIM + lane * 4 + 1] = s1.y;
  red[group * DIM + lane * 4 + 2] = s1.z;
  red[group * DIM + lane * 4 + 3] = s1.w;
  red[1024 + group * DIM + lane * 4 + 0] = s2.x;
  red[1024 + group * DIM + lane * 4 + 1] = s2.y;
  red[1024 + group * DIM + lane * 4 + 2] = s2.z;
  red[1024 + group * DIM + lane * 4 + 3] = s2.w;
  __syncthreads();
  if (tid < DIM) {
    float a = 0.f, b = 0.f;
#pragma unroll
    for (int g = 0; g < 8; ++g) {
      a += red[g * DIM + tid];
      b += red[1024 + g * DIM + tid];
    }
    atomicAdd(&stats[tid], a);
    atomicAdd(&stats[DIM + tid], b);
  }
}

// ---------------------------------------------------------------------------
// Fold (sum, sumsq) -> (a = g*rsqrt(var+eps), c = b - mu*a). One block.
// ---------------------------------------------------------------------------
__global__ void bn_param(const float* __restrict__ stats,
                         const float* __restrict__ g,
                         const float* __restrict__ b, float* __restrict__ ac) {
  const int j = threadIdx.x;
  const float invN = 1.0f / (float)N_NODES;
  const float mu = stats[j] * invN;
  const float var = stats[DIM + j] * invN - mu * mu;
  const float a = g[j] * rsqrtf(var + BN_EPS);
  ac[j] = a;
  ac[DIM + j] = b[j] - mu * a;
}

// ---------------------------------------------------------------------------
// h = (relu?)(a[k]*t + c[k]) elementwise; one float4 per thread, exact grid.
// ---------------------------------------------------------------------------
template <int RELU>
__global__ __launch_bounds__(256) void apply_bn(const float* __restrict__ t,
                                                const float* __restrict__ ac,
                                                float* __restrict__ out) {
  const int i = blockIdx.x * blockDim.x + threadIdx.x;
  const int k = (i * 4) & (DIM - 1);
  const float4 v = *reinterpret_cast<const float4*>(&t[(size_t)i * 4]);
  const float4 a = *reinterpret_cast<const float4*>(&ac[k]);
  const float4 c = *reinterpret_cast<const float4*>(&ac[DIM + k]);
  float4 r;
  r.x = a.x * v.x + c.x;
  r.y = a.y * v.y + c.y;
  r.z = a.z * v.z + c.z;
  r.w = a.w * v.w + c.w;
  if (RELU) {
    r.x = fmaxf(r.x, 0.f);
    r.y = fmaxf(r.y, 0.f);
    r.z = fmaxf(r.z, 0.f);
    r.w = fmaxf(r.w, 0.f);
  }
  *reinterpret_cast<float4*>(&out[(size_t)i * 4]) = r;
}

extern "C" void kernel_launch(void* const* d_in, const int* in_sizes, int n_in,
                              void* d_out, int out_size, void* d_ws,
                              size_t ws_size, hipStream_t stream) {
  const float* x = (const float*)d_in[0];
  const int* ei = (const int*)d_in[1];  // [2][E]: src = ei, dst = ei+E
  const float* eps = (const float*)d_in[2];
  const float* W1 = (const float*)d_in[3];
  const float* b1 = (const float*)d_in[4];
  const float* g1 = (const float*)d_in[5];
  const float* bb1 = (const float*)d_in[6];
  const float* W2 = (const float*)d_in[7];
  const float* b2 = (const float*)d_in[8];
  const float* g2 = (const float*)d_in[9];
  const float* bb2 = (const float*)d_in[10];

  const int E = in_sizes[1] / 2;
  const size_t ND = (size_t)N_NODES * DIM;

  float* bufZ = (float*)d_ws;              // z / t buffer (25.6 MB)
  float* bufH = bufZ + ND;                 // h ping buffer (25.6 MB)
  float* stats = bufH + ND;                // 512 floats
  float* bnp = stats + 512;                // 512 floats (a1,c1,a2,c2)
  int* cnt = (int*)(bnp + 512);            // [N]
  int* row_ptr = cnt + N_NODES;            // [N+1]
  int* cur = row_ptr + N_NODES + 1;        // [N]
  int* srcl = cur + N_NODES;               // [E]

  const int gemm_grid = (N_NODES + 63) / 64;         // 782
  const int apply_grid = (N_NODES * DIM / 4) / 256;  // 6250 (exact)
  const int edge_grid = (E + 255) / 256;             // 3125
  const int agg_grid = (N_NODES * 64 + 255) / 256;   // 12500

  // ---- CSR build (once; graph constant across layers)
  hipMemsetAsync(cnt, 0, sizeof(int) * (size_t)N_NODES * 2 + sizeof(int),
                 stream);  // cnt + row_ptr[0..?]; cur zeroed separately
  hipMemsetAsync(cur, 0, sizeof(int) * (size_t)N_NODES, stream);
  edge_hist<<<edge_grid, 256, 0, stream>>>(ei + E, cnt, E);
  edge_scan<<<1, 1024, 0, stream>>>(cnt, row_ptr);
  edge_fill<<<edge_grid, 256, 0, stream>>>(ei, ei + E, row_ptr, cur, srcl, E);

  const float* h = x;
  for (int l = 0; l < 3; ++l) {
    hipMemsetAsync(stats, 0, sizeof(float) * 512, stream);
    aggregate_combine<<<agg_grid, 256, 0, stream>>>(h, row_ptr, srcl, eps + l,
                                                    bufZ);
    gemm_bn<2><<<gemm_grid, 256, 0, stream>>>(bufZ, nullptr,
                                              W1 + (size_t)l * DIM * DIM,
                                              b1 + l * DIM, bufZ, stats);
    bn_param<<<1, DIM, 0, stream>>>(stats, g1 + l * DIM, bb1 + l * DIM, bnp);
    gemm_bn<1><<<gemm_grid, 256, 0, stream>>>(bufZ, bnp,
                                              W2 + (size_t)l * DIM * DIM,
                                              b2 + l * DIM, bufZ, stats + 256);
    bn_param<<<1, DIM, 0, stream>>>(stats + 256, g2 + l * DIM, bb2 + l * DIM,
                                    bnp + 256);
    if (l < 2) {
      apply_bn<1><<<apply_grid, 256, 0, stream>>>(bufZ, bnp + 256, bufH);
      h = bufH;
    } else {
      apply_bn<0><<<apply_grid, 256, 0, stream>>>(bufZ, bnp + 256,
                                                  (float*)d_out);
    }
  }
}